// Round 1
// baseline (465.936 us; speedup 1.0000x reference)
//
#include <hip/hip_runtime.h>
#include <hip/hip_bf16.h>

#define BIGF 1e30f
#define TC 80   // channels
#define TN 512  // sequence length (N == M)

// ---------------------------------------------------------------------------
// Kernel 1: pairwise squared distances D[b][n][m] = ||x[b,:,n] - y[b,:,m]||^2
// Tiled 64x64 per block, 256 threads, 4x4 register blocking, fp32 VALU.
// ---------------------------------------------------------------------------
__global__ __launch_bounds__(256) void pairdist_kernel(
    const float* __restrict__ x, const float* __restrict__ y,
    float* __restrict__ D) {
  const int b  = blockIdx.z;
  const int n0 = blockIdx.x * 64;
  const int m0 = blockIdx.y * 64;

  __shared__ float xs[TC][64];
  __shared__ float ys[TC][64];
  __shared__ float xxs[64];
  __shared__ float yys[64];

  const float* xb = x + (size_t)b * TC * TN;
  const float* yb = y + (size_t)b * TC * TN;
  const int tid = threadIdx.x;

  // Stage tiles: 80 x 64, coalesced (64 consecutive floats per row)
  for (int idx = tid; idx < TC * 64; idx += 256) {
    int c = idx >> 6, n = idx & 63;
    xs[c][n] = xb[c * TN + n0 + n];
    ys[c][n] = yb[c * TN + m0 + n];
  }
  __syncthreads();

  // Row/col squared norms
  if (tid < 64) {
    float s = 0.f;
    for (int c = 0; c < TC; ++c) { float v = xs[c][tid]; s += v * v; }
    xxs[tid] = s;
  } else if (tid < 128) {
    int t2 = tid - 64;
    float s = 0.f;
    for (int c = 0; c < TC; ++c) { float v = ys[c][t2]; s += v * v; }
    yys[t2] = s;
  }
  __syncthreads();

  // 4x4 register block per thread; tm fastest so stores coalesce
  const int tm = tid & 15, tn = tid >> 4;
  float acc[4][4] = {};
  for (int c = 0; c < TC; ++c) {
    float4 xa = *(const float4*)&xs[c][tn * 4];
    float4 ya = *(const float4*)&ys[c][tm * 4];
    float xv[4] = {xa.x, xa.y, xa.z, xa.w};
    float yv[4] = {ya.x, ya.y, ya.z, ya.w};
#pragma unroll
    for (int a = 0; a < 4; ++a)
#pragma unroll
      for (int q = 0; q < 4; ++q) acc[a][q] += xv[a] * yv[q];
  }

  float* Dbase = D + (size_t)b * TN * TN;
#pragma unroll
  for (int a = 0; a < 4; ++a) {
    int n = n0 + tn * 4 + a;
    float xxv = xxs[tn * 4 + a];
    float4 o;
    o.x = xxv + yys[tm * 4 + 0] - 2.f * acc[a][0];
    o.y = xxv + yys[tm * 4 + 1] - 2.f * acc[a][1];
    o.z = xxv + yys[tm * 4 + 2] - 2.f * acc[a][2];
    o.w = xxv + yys[tm * 4 + 3] - 2.f * acc[a][3];
    *(float4*)&Dbase[(size_t)n * TN + m0 + tm * 4] = o;
  }
}

// ---------------------------------------------------------------------------
// Kernel 2: soft-DTW anti-diagonal sweep. One block per batch, 512 threads
// (thread t handles matrix row i = t+1). Diagonals live in registers:
//   prev     = R_{d-1}[i]
//   prev2m1  = R_{d-2}[i-1]   (== last step's "up")
//   up       = R_{d-1}[i-1]   (shfl_up; wave-boundary via LDS slot)
// One __syncthreads per diagonal; boundary slot parity-double-buffered and
// read post-barrier into a register for the NEXT iteration (off the chain).
// D prefetched 2 diagonals ahead.
// ---------------------------------------------------------------------------
__global__ __launch_bounds__(512) void sdtw_kernel(
    const float* __restrict__ D, float* __restrict__ out) {
  const int b = blockIdx.x;
  const int t = threadIdx.x;        // i = t + 1
  const int lane = t & 63;
  const int w = t >> 6;

  __shared__ float bslot[2][12];    // slot[w] read by wave w; wave w writes slot[w+1]
  if (t == 0) { bslot[0][0] = BIGF; bslot[1][0] = BIGF; }
  __syncthreads();

  const float* Db = D + (size_t)b * TN * TN + (size_t)t * TN;  // row i-1 = t

  float prev    = BIGF;                    // R_1[i] (all BIG)
  float prev2m1 = (t == 0) ? 0.f : BIGF;   // R_0[i-1]
  float bprev   = BIGF;                    // boundary value for next iter (wave0: always BIG)

  auto clampi = [](int v) { return v < 0 ? 0 : (v > TN - 1 ? TN - 1 : v); };
  // D offset for diagonal d at this thread: od = d - t - 2, valid iff 0..511
  float dn1 = Db[clampi(2 - t - 2)];
  float dn2 = Db[clampi(3 - t - 2)];

  for (int d = 2; d <= 2 * TN; ++d) {
    float up = __shfl_up(prev, 1, 64);
    if (lane == 0) up = bprev;

    float r0 = prev2m1, r1 = up, r2 = prev;
    float m3 = fminf(fminf(r0, r1), r2);
    float s  = __expf(m3 - r0) + __expf(m3 - r1) + __expf(m3 - r2);
    float sm = m3 - __logf(s);             // gamma = 1

    float dval = dn1;
    dn1 = dn2;
    dn2 = Db[clampi(d + 2 - t - 2)];       // prefetch 2 ahead (clamped, in-bounds)

    float cur = ((unsigned)(d - t - 2) <= (unsigned)(TN - 1)) ? (dval + sm) : BIGF;

    prev2m1 = up;
    if (lane == 63) bslot[d & 1][w + 1] = cur;
    prev = cur;
    __syncthreads();
    bprev = bslot[d & 1][w];               // consumed at iteration d+1
  }

  if (t == TN - 1) out[b] = prev;          // R[512][512]
}

extern "C" void kernel_launch(void* const* d_in, const int* in_sizes, int n_in,
                              void* d_out, int out_size, void* d_ws, size_t ws_size,
                              hipStream_t stream) {
  const float* x = (const float*)d_in[0];
  const float* y = (const float*)d_in[1];
  float* out = (float*)d_out;
  float* D = (float*)d_ws;  // 32*512*512*4 = 33.5 MB

  dim3 g1(TN / 64, TN / 64, 32);
  pairdist_kernel<<<g1, 256, 0, stream>>>(x, y, D);
  sdtw_kernel<<<32, 512, 0, stream>>>(D, out);
}